// Round 1
// 176.652 us; speedup vs baseline: 1.0128x; 1.0128x over previous
//
#include <hip/hip_runtime.h>
#include <math.h>

#ifndef TAU_CONST
#define TAU_CONST 1.0f
#endif

// Fast rbox -> (mu, Sigma, det) using double-angle identities.
// det(R S R^T) == det(S) == a*b exactly (rotation-invariant), so we never
// form s00*s11 - s01^2 (cheaper AND numerically exact).
__device__ __forceinline__ void rbox_to_gauss(float x, float y, float w, float h, float r,
                                              float& mx, float& my,
                                              float& s00, float& s01, float& s11, float& det) {
    w = fminf(fmaxf(w, 1e-7f), 1e7f);
    h = fminf(fmaxf(h, 1e-7f), 1e7f);
    float a = 0.25f * w * w;   // (w/2)^2
    float b = 0.25f * h * h;   // (h/2)^2
    float s2, c2;
    __sincosf(r + r, &s2, &c2);          // sin 2r, cos 2r (native v_sin/v_cos)
    float hs = 0.5f * (a + b);
    float hd = 0.5f * (a - b);
    s00 = fmaf(hd, c2, hs);              // a c^2 + b s^2
    s11 = fmaf(-hd, c2, hs);             // a s^2 + b c^2
    s01 = hd * s2;                       // (a-b) s c
    det = a * b;
    mx = x; my = y;
}

__device__ __forceinline__ float kld_row(const float* p, const float* t) {
    float pmx, pmy, p00, p01, p11, dp;
    float tmx, tmy, t00, t01, t11, dt;
    rbox_to_gauss(p[0], p[1], p[2], p[3], p[4], pmx, pmy, p00, p01, p11, dp);
    rbox_to_gauss(t[0], t[1], t[2], t[3], t[4], tmx, tmy, t00, t01, t11, dt);
    float dx = pmx - tmx, dy = pmy - tmy;
    float inv_dt = __builtin_amdgcn_rcpf(dt);   // v_rcp_f32, ~1 ulp
    float inv_dp = __builtin_amdgcn_rcpf(dp);
    // delta^T Sigma_t^{-1} delta  (adjugate / det form)
    float term1 = (dx * dx * t11 - 2.0f * dx * dy * t01 + dy * dy * t00) * inv_dt;
    // trace(Sigma_t^{-1} Sigma_p)
    float tr = (t11 * p00 + t00 * p11 - 2.0f * t01 * p01) * inv_dt;
    // log(dt/dp): one v_rcp + one v_log instead of precise div + precise logf
    float term2 = tr + __logf(dt * inv_dp);
    float dis = term1 + term2 - 2.0f;
    float kl = fmaxf(dis, 1e-6f);
    // log1p(kl) -> __logf(1+kl): kl >= 1e-6, abs error ~1e-7, irrelevant here
    float l1p = __logf(1.0f + kl);
    return 1.0f - __builtin_amdgcn_rcpf(TAU_CONST + l1p);
}

// One thread handles 4 consecutive rows: 4 rows * 5 floats = 5 float4 loads per input.
__global__ void __launch_bounds__(256) gdloss_vec4_kernel(const float* __restrict__ pred,
                                                          const float* __restrict__ target,
                                                          float* __restrict__ out, int n4) {
    int tid = blockIdx.x * blockDim.x + threadIdx.x;
    if (tid >= n4) return;
    const float4* pp = (const float4*)pred;
    const float4* tp = (const float4*)target;
    float4 pv[5], tv[5];
#pragma unroll
    for (int k = 0; k < 5; ++k) {
        pv[k] = pp[5 * tid + k];
        tv[k] = tp[5 * tid + k];
    }
    const float* pf = (const float*)pv;
    const float* tf = (const float*)tv;
    float4 o;
    o.x = kld_row(pf + 0,  tf + 0);
    o.y = kld_row(pf + 5,  tf + 5);
    o.z = kld_row(pf + 10, tf + 10);
    o.w = kld_row(pf + 15, tf + 15);
    ((float4*)out)[tid] = o;
}

// Scalar tail (n % 4 rows), only launched if needed.
__global__ void gdloss_tail_kernel(const float* __restrict__ pred,
                                   const float* __restrict__ target,
                                   float* __restrict__ out, int start, int n) {
    int i = start + blockIdx.x * blockDim.x + threadIdx.x;
    if (i >= n) return;
    float p[5], t[5];
#pragma unroll
    for (int k = 0; k < 5; ++k) {
        p[k] = pred[5 * i + k];
        t[k] = target[5 * i + k];
    }
    out[i] = kld_row(p, t);
}

extern "C" void kernel_launch(void* const* d_in, const int* in_sizes, int n_in,
                              void* d_out, int out_size, void* d_ws, size_t ws_size,
                              hipStream_t stream) {
    const float* pred   = (const float*)d_in[0];
    const float* target = (const float*)d_in[1];
    float* out = (float*)d_out;
    int n = in_sizes[0] / 5;   // number of rows
    int n4 = n / 4;
    if (n4 > 0) {
        int blocks = (n4 + 255) / 256;
        gdloss_vec4_kernel<<<blocks, 256, 0, stream>>>(pred, target, out, n4);
    }
    int rem = n - n4 * 4;
    if (rem > 0) {
        gdloss_tail_kernel<<<1, 64, 0, stream>>>(pred, target, out, n4 * 4, n);
    }
}